// Round 6
// baseline (1246.311 us; speedup 1.0000x reference)
//
#include <hip/hip_runtime.h>

// Problem constants (from reference setup_inputs)
static constexpr int B = 32;
static constexpr int P = 19248;
static constexpr int G = 32;
static constexpr int C = 41;          // num classes
static constexpr float POS_TH = 0.5f;
static constexpr float NEG_TH = 0.4f;

static constexpr int TM = 128;                   // k_mega block size
static constexpr int PBM = (P + TM - 1) / TM;    // 151 tiles per batch
static constexpr int NPART = 8;                  // k_match prior partitions
static constexpr int PPART = P / NPART;          // 2406 (exact)
static constexpr int P4 = P / 4;                 // 4812 float4 per batch

__device__ __forceinline__ float sl1(float d) {
    d = fabsf(d);
    return d < 1.0f ? 0.5f * d * d : d - 0.5f;
}

// ---------------------------------------------------------------------------
// Kernel 1: per (b,g) best prior, p-major. Grid (NPART, B) x 1024 = 256
// blocks (1/CU). Each thread scans its prior stride ONCE (point-form +
// area amortized over all 32 gts) keeping 32 statically-indexed running
// (best,idx) pairs in registers; 32 packed-u64 wave reduces -> LDS -> store.
// PPART=2406 >= 1024 so every thread has >=2 iters -> best >= 0 always
// (sign bit never set, uint packing order-safe). Also zeroes the counters.
// ---------------------------------------------------------------------------
__global__ __launch_bounds__(1024) void k_match(
    const float* __restrict__ priors, const float* __restrict__ gt,
    unsigned long long* __restrict__ bp_part, int* __restrict__ counters) {
    int part = blockIdx.x, b = blockIdx.y;
    int tid = threadIdx.x;
    if (part == 0 && b == 0 && tid < B + 1) counters[tid] = 0;  // done + bdone[32]
    __shared__ float4 sg[G];
    __shared__ float sarea[G];
    __shared__ unsigned long long swave[G][16];
    if (tid < G) {
        float4 g4 = reinterpret_cast<const float4*>(gt)[b * G + tid];
        sg[tid] = g4;
        sarea[tid] = (g4.z - g4.x) * (g4.w - g4.y);
    }
    __syncthreads();

    float best[G]; int bidx[G];
#pragma unroll
    for (int g = 0; g < G; ++g) { best[g] = -1.0f; bidx[g] = 0; }
    for (int i = tid; i < PPART; i += 1024) {
        int p = part * PPART + i;
        float4 pr = reinterpret_cast<const float4*>(priors)[p];
        float px1 = pr.x - pr.z * 0.5f, py1 = pr.y - pr.w * 0.5f;
        float px2 = pr.x + pr.z * 0.5f, py2 = pr.y + pr.w * 0.5f;
        float parea = (px2 - px1) * (py2 - py1);
#pragma unroll
        for (int g = 0; g < G; ++g) {
            float4 gb = sg[g];
            float lx = fmaxf(gb.x, px1), ly = fmaxf(gb.y, py1);
            float rx = fminf(gb.z, px2), ry = fminf(gb.w, py2);
            float w = fmaxf(rx - lx, 0.0f), h = fmaxf(ry - ly, 0.0f);
            float inter = w * h;
            float iou = inter / (sarea[g] + parea - inter);
            if (iou > best[g]) { best[g] = iou; bidx[g] = p; }  // ascending p: first max
        }
    }
    int lane = tid & 63, wid = tid >> 6;
#pragma unroll
    for (int g = 0; g < G; ++g) {
        // (iou_bits<<32) | ~p : higher IoU wins, then smaller p (argmax first-occurrence)
        unsigned long long pk =
            ((unsigned long long)__float_as_uint(best[g]) << 32)
            | (unsigned)(0xFFFFFFFFu - (unsigned)bidx[g]);
#pragma unroll
        for (int d = 32; d; d >>= 1) {
            unsigned long long o = __shfl_xor(pk, d);
            if (o > pk) pk = o;
        }
        if (lane == 0) swave[g][wid] = pk;
    }
    __syncthreads();
    if (tid < G) {
        unsigned long long mx = swave[tid][0];
#pragma unroll
        for (int w2 = 1; w2 < 16; ++w2) {
            unsigned long long v = swave[tid][w2];
            if (v > mx) mx = v;
        }
        bp_part[(part * B + b) * G + tid] = mx;
    }
}

// ---------------------------------------------------------------------------
// Kernel 2 (mega): main streaming + per-batch topk continuation + final.
// Main phase: per (b,p) inline IoU argmax over G, forced-prior override
// (8-part max combine), box loss, CE loss, mined value; conf staged
// global->reg (static float4 x11) -> LDS. Block partial -> plain store.
// Continuation (last block of batch b via bdone counter): 3-level radix
// select (11+11+10 bits, 2048-bin hist overlaid on sconf) + sum pass ->
// neg_b[b]. Final (last of 32 continuations): reduce partials + neg_b -> out.
// ---------------------------------------------------------------------------
__global__ __launch_bounds__(TM) void k_mega(
    const float* __restrict__ loc_data, const float* __restrict__ conf_data,
    const float* __restrict__ priors, const float* __restrict__ gt,
    const int* __restrict__ labels,
    const unsigned long long* __restrict__ bp_part,
    float* __restrict__ mined, float4* __restrict__ partial,
    float* __restrict__ neg_b, int* __restrict__ counters,
    float* __restrict__ out) {
    int b = blockIdx.y;
    int p0 = blockIdx.x * TM;
    int tid = threadIdx.x;
    int p = p0 + tid;
    int lane = tid & 63, wid = tid >> 6;
    __shared__ float sconf[TM * C];        // 21 KB; overlaid by hist in continuation
    __shared__ int sforce[G];
    __shared__ float4 sg[G];
    __shared__ float sarea[G];
    if (tid < G) {
        unsigned long long mx = 0ull;
#pragma unroll
        for (int q = 0; q < NPART; ++q) {
            unsigned long long v = bp_part[(q * B + b) * G + tid];
            mx = v > mx ? v : mx;
        }
        sforce[tid] = (int)(0xFFFFFFFFu - (unsigned)mx);
        float4 g4 = reinterpret_cast<const float4*>(gt)[b * G + tid];
        sg[tid] = g4;
        sarea[tid] = (g4.z - g4.x) * (g4.w - g4.y);
    }
    int valid = min(TM, P - p0);
    size_t gbase = ((size_t)b * P + p0) * C;
    int tot4 = (valid * C) >> 2;          // exact: 128*41 and 48*41 both %4==0
    const float4* g4p = reinterpret_cast<const float4*>(conf_data + gbase);
    float4* s4 = reinterpret_cast<float4*>(sconf);
    float4 r0, r1, r2, r3, r4, r5, r6, r7, r8, r9, r10;
#define LD(j, rj) { int i = tid + (j) * TM; if (i < tot4) rj = g4p[i]; }
#define ST(j, rj) { int i = tid + (j) * TM; if (i < tot4) s4[i] = rj; }
    LD(0, r0) LD(1, r1) LD(2, r2) LD(3, r3) LD(4, r4) LD(5, r5)
    LD(6, r6) LD(7, r7) LD(8, r8) LD(9, r9) LD(10, r10)
    ST(0, r0) ST(1, r1) ST(2, r2) ST(3, r3) ST(4, r4) ST(5, r5)
    ST(6, r6) ST(7, r7) ST(8, r8) ST(9, r9) ST(10, r10)
#undef LD
#undef ST
    __syncthreads();

    float my_box = 0.0f, my_posc = 0.0f; int my_pos = 0;
    if (p < P) {
        float4 pr = reinterpret_cast<const float4*>(priors)[p];
        float px1 = pr.x - pr.z * 0.5f, py1 = pr.y - pr.w * 0.5f;
        float px2 = pr.x + pr.z * 0.5f, py2 = pr.y + pr.w * 0.5f;
        float parea = (px2 - px1) * (py2 - py1);
        float ov = -1.0f; int bidx = 0;
#pragma unroll
        for (int g = 0; g < G; ++g) {
            float4 gb = sg[g];
            float lx = fmaxf(gb.x, px1), ly = fmaxf(gb.y, py1);
            float rx = fminf(gb.z, px2), ry = fminf(gb.w, py2);
            float w = fmaxf(rx - lx, 0.0f), h = fmaxf(ry - ly, 0.0f);
            float inter = w * h;
            float iou = inter / (sarea[g] + parea - inter);
            if (iou > ov) { ov = iou; bidx = g; }   // strict > keeps FIRST g
        }
        int fidx = -1;
#pragma unroll
        for (int g = 0; g < G; ++g)
            if (p == sforce[g]) fidx = g;             // ascending g: LAST wins
        bool pos = false, neutral = false;
        int gidx = 0, cls = 0;
        float boxl = 0.0f;
        if (fidx >= 0)            { pos = true; gidx = fidx; }
        else if (ov >= POS_TH)    { pos = true; gidx = bidx; }
        else if (ov >= NEG_TH)    { neutral = true; }
        if (pos) {
            cls = labels[b * G + gidx] + 1;
            float4 gb = sg[gidx];
            float mcx = (gb.x + gb.z) * 0.5f, mcy = (gb.y + gb.w) * 0.5f;
            float tx = (mcx - pr.x) / (0.1f * pr.z);
            float ty = (mcy - pr.y) / (0.1f * pr.w);
            float tw = __logf(fmaxf((gb.z - gb.x) / pr.z, 1e-8f)) / 0.2f;
            float th = __logf(fmaxf((gb.w - gb.y) / pr.w, 1e-8f)) / 0.2f;
            float4 ld = reinterpret_cast<const float4*>(loc_data)[b * P + p];
            boxl = sl1(ld.x - tx) + sl1(ld.y - ty) + sl1(ld.z - tw) + sl1(ld.w - th);
        }
        const float* cv = &sconf[tid * C];
        float mx = cv[0];
#pragma unroll
        for (int c = 1; c < C; ++c) mx = fmaxf(mx, cv[c]);
        float se = 0.0f;
#pragma unroll
        for (int c = 0; c < C; ++c) se += __expf(cv[c] - mx);
        float lse = mx + __logf(se);
        float lc = lse - cv[cls];          // >= 0 always (lse >= mx >= picked)
        mined[(size_t)b * P + p] = (pos || neutral) ? 0.0f : lc;
        my_pos = pos ? 1 : 0;
        my_box = boxl;
        my_posc = pos ? lc : 0.0f;
    }

#pragma unroll
    for (int d = 32; d; d >>= 1) {
        my_box  += __shfl_xor(my_box, d);
        my_posc += __shfl_xor(my_posc, d);
        my_pos  += __shfl_xor(my_pos, d);
    }
    __shared__ float rb[2], rc[2]; __shared__ int rp[2];
    if (lane == 0) { rb[wid] = my_box; rc[wid] = my_posc; rp[wid] = my_pos; }
    __syncthreads();

    // ---- election: last block of batch b continues into topk ----
    __shared__ bool amlast;
    if (tid == 0) {
        partial[b * PBM + blockIdx.x] =
            make_float4(rb[0] + rb[1], rc[0] + rc[1], (float)(rp[0] + rp[1]), 0.0f);
        __threadfence();                              // release mined+partial
        int old = atomicAdd(&counters[1 + b], 1);
        amlast = (old == PBM - 1);
    }
    __syncthreads();
    if (!amlast) return;
    __threadfence();                                  // acquire others' stores

    // ================= continuation: topk for batch b =================
    const float4* mb4 = reinterpret_cast<const float4*>(mined + (size_t)b * P);
    int cnt = 0;
    for (int i = tid; i < PBM; i += TM) cnt += (int)partial[b * PBM + i].z;
#pragma unroll
    for (int d = 32; d; d >>= 1) cnt += __shfl_xor(cnt, d);
    __shared__ int ired[2];
    if (lane == 0) ired[wid] = cnt;
    __syncthreads();
    int np = ired[0] + ired[1];
    int k = 3 * np; if (k > P - 1) k = P - 1;

    float negval = 0.0f;                  // valid on tid 0
    if (k > 0) {                          // block-uniform
        unsigned* hist = reinterpret_cast<unsigned*>(sconf);   // 2048 bins overlay
        __shared__ unsigned sel[3];       // [0]=prefix, [1]=want, [2]=cnt_gt
        __shared__ unsigned usuf[2];
        if (tid == 0) { sel[0] = 0u; sel[1] = (unsigned)k; sel[2] = 0u; }
        const int shifts[3] = {21, 10, 0};
        const int widths[3] = {11, 11, 10};
#pragma unroll
        for (int level = 0; level < 3; ++level) {
            int shift = shifts[level];
            unsigned bmask = (1u << widths[level]) - 1u;
            for (int i = tid; i < 2048; i += TM) hist[i] = 0u;
            __syncthreads();
            unsigned pref = sel[0];
            unsigned pmask = level ? (0xFFFFFFFFu << (shift + widths[level])) : 0u;
            for (int i = tid; i < P4; i += TM) {
                float4 v4 = mb4[i];
                unsigned v;
                v = __float_as_uint(v4.x); if ((v & pmask) == pref) atomicAdd(&hist[(v >> shift) & bmask], 1u);
                v = __float_as_uint(v4.y); if ((v & pmask) == pref) atomicAdd(&hist[(v >> shift) & bmask], 1u);
                v = __float_as_uint(v4.z); if ((v & pmask) == pref) atomicAdd(&hist[(v >> shift) & bmask], 1u);
                v = __float_as_uint(v4.w); if ((v & pmask) == pref) atomicAdd(&hist[(v >> shift) & bmask], 1u);
            }
            __syncthreads();
            // selection: thread owns bins [16*tid, 16*tid+16)
            unsigned tsum = 0;
#pragma unroll
            for (int j = 0; j < 16; ++j) tsum += hist[16 * tid + j];
            unsigned x = tsum;
#pragma unroll
            for (int d = 1; d < 64; d <<= 1) {
                unsigned t = __shfl_down(x, d);
                if (lane + d < 64) x += t;
            }
            if (lane == 0) usuf[wid] = x;             // per-wave total
            __syncthreads();
            unsigned S_own = x + ((wid == 0) ? usuf[1] : 0u);  // suffix incl own bins
            unsigned want = sel[1];
            __syncthreads();                          // all read want before writes
            unsigned cur = S_own - tsum;              // S(16t+16)
#pragma unroll
            for (int j = 15; j >= 0; --j) {
                unsigned h = hist[16 * tid + j];
                unsigned nxt = cur + h;
                if (cur < want && want <= nxt) {      // unique crossing bin
                    sel[0] = pref | (((unsigned)(16 * tid + j) & bmask) << shift);
                    sel[1] = want - cur;
                    sel[2] += cur;
                }
                cur = nxt;
            }
            __syncthreads();
        }
        unsigned vk = sel[0];
        unsigned cnt_gt = sel[2];
        float vkf = __uint_as_float(vk);
        float ssum = 0.0f;
        for (int i = tid; i < P4; i += TM) {
            float4 v4 = mb4[i];
            if (__float_as_uint(v4.x) > vk) ssum += v4.x;
            if (__float_as_uint(v4.y) > vk) ssum += v4.y;
            if (__float_as_uint(v4.z) > vk) ssum += v4.z;
            if (__float_as_uint(v4.w) > vk) ssum += v4.w;
        }
#pragma unroll
        for (int d = 32; d; d >>= 1) ssum += __shfl_xor(ssum, d);
        __shared__ float fs[2];
        if (lane == 0) fs[wid] = ssum;
        __syncthreads();
        if (tid == 0)
            negval = fs[0] + fs[1] + (float)(k - (int)cnt_gt) * vkf;
    }

    // ---- publish neg_b, last continuation finalizes ----
    __shared__ bool amfinal;
    if (tid == 0) {
        neg_b[b] = negval;
        __threadfence();
        int old = atomicAdd(&counters[0], 1);
        amfinal = (old == B - 1);
    }
    __syncthreads();
    if (!amfinal) return;
    __threadfence();

    float sbx = 0.0f, sc = 0.0f, sp2 = 0.0f, sn = 0.0f;
    for (int i = tid; i < B * PBM; i += TM) {
        float4 v = partial[i];
        sbx += v.x; sc += v.y; sp2 += v.z;
    }
    if (tid < B) sn = neg_b[tid];
#pragma unroll
    for (int d = 32; d; d >>= 1) {
        sbx += __shfl_xor(sbx, d);
        sc  += __shfl_xor(sc, d);
        sp2 += __shfl_xor(sp2, d);
        sn  += __shfl_xor(sn, d);
    }
    __shared__ float fr[2][4];
    if (lane == 0) { fr[wid][0] = sbx; fr[wid][1] = sc; fr[wid][2] = sp2; fr[wid][3] = sn; }
    __syncthreads();
    if (tid == 0) {
        float tb = fr[0][0] + fr[1][0], tc = fr[0][1] + fr[1][1];
        float tp = fr[0][2] + fr[1][2], tn = fr[0][3] + fr[1][3];
        float npos = fmaxf(tp, 1.0f);
        out[0] = tb / npos * 1.5f + (tc + tn) / npos * 6.5f;
    }
}

extern "C" void kernel_launch(void* const* d_in, const int* in_sizes, int n_in,
                              void* d_out, int out_size, void* d_ws, size_t ws_size,
                              hipStream_t stream) {
    const float* loc    = (const float*)d_in[0];
    const float* conf   = (const float*)d_in[1];
    const float* priors = (const float*)d_in[2];
    const float* gt     = (const float*)d_in[3];
    const int*   labels = (const int*)d_in[4];
    float* out = (float*)d_out;

    char* w = (char*)d_ws;
    float4* partial = (float4*)w;                      w += sizeof(float4) * B * PBM;
    float* mined  = (float*)w;                         w += sizeof(float) * B * P;
    unsigned long long* bp_part = (unsigned long long*)w;
    w += sizeof(unsigned long long) * NPART * B * G;
    float* negb   = (float*)w;                         w += sizeof(float) * B;
    int*   counters = (int*)w;                         w += sizeof(int) * (B + 1);

    // 2 graph nodes. bp_part/partial/mined/negb are fully overwritten each
    // call; counters zeroed inside k_match.
    k_match<<<dim3(NPART, B), 1024, 0, stream>>>(priors, gt, bp_part, counters);
    k_mega<<<dim3(PBM, B), TM, 0, stream>>>(loc, conf, priors, gt, labels,
                                            bp_part, mined, partial,
                                            negb, counters, out);
}

// Round 7
// 257.390 us; speedup vs baseline: 4.8421x; 4.8421x over previous
//
#include <hip/hip_runtime.h>

// Problem constants (from reference setup_inputs)
static constexpr int B = 32;
static constexpr int P = 19248;
static constexpr int G = 32;
static constexpr int C = 41;          // num classes
static constexpr float POS_TH = 0.5f;
static constexpr float NEG_TH = 0.4f;

static constexpr int TM = 128;                   // k_mega block size
static constexpr int PBM = (P + TM - 1) / TM;    // 151 tiles per batch
static constexpr int NPART = 8;                  // k_match prior partitions
static constexpr int PPART = P / NPART;          // 2406 (exact)
static constexpr int P4 = P / 4;                 // 4812 float4 per batch
static constexpr int CPAD = 32;                  // counter stride (ints) = 128 B

__device__ __forceinline__ float sl1(float d) {
    d = fabsf(d);
    return d < 1.0f ? 0.5f * d * d : d - 0.5f;
}

// ---------------------------------------------------------------------------
// Kernel 1: per (b,g) best prior (R5-proven wave-per-g form — no register
// arrays, no spill). Grid (NPART, B) x 1024. Wave w handles g = w, w+16 over
// its prior part: per-lane running best (ascending p + strict > = first-max),
// then packed-u64 wave reduce ((iou_bits<<32)|~p). Plain stores, no atomics.
// Block (0,0) zeroes the PADDED completion counters (one 128B line each).
// ---------------------------------------------------------------------------
__global__ __launch_bounds__(1024) void k_match(
    const float* __restrict__ priors, const float* __restrict__ gt,
    unsigned long long* __restrict__ bp_part, int* __restrict__ counters) {
    int part = blockIdx.x, b = blockIdx.y;
    if (part == 0 && b == 0 && threadIdx.x < B + 1)
        counters[threadIdx.x * CPAD] = 0;       // done + bdone[32], 1 line each
    int lane = threadIdx.x & 63, wid = threadIdx.x >> 6;
    int pbase = part * PPART;
#pragma unroll
    for (int gsub = 0; gsub < 2; ++gsub) {
        int g = wid + gsub * 16;
        float4 gb = reinterpret_cast<const float4*>(gt)[b * G + g]; // broadcast
        float ga = (gb.z - gb.x) * (gb.w - gb.y);
        float best = -1.0f; int bidx = 0;
        for (int i = lane; i < PPART; i += 64) {
            int p = pbase + i;
            float4 pr = reinterpret_cast<const float4*>(priors)[p];
            float px1 = pr.x - pr.z * 0.5f, py1 = pr.y - pr.w * 0.5f;
            float px2 = pr.x + pr.z * 0.5f, py2 = pr.y + pr.w * 0.5f;
            float parea = (px2 - px1) * (py2 - py1);
            float lx = fmaxf(gb.x, px1), ly = fmaxf(gb.y, py1);
            float rx = fminf(gb.z, px2), ry = fminf(gb.w, py2);
            float w = fmaxf(rx - lx, 0.0f), h = fmaxf(ry - ly, 0.0f);
            float inter = w * h;
            float iou = inter / (ga + parea - inter);
            if (iou > best) { best = iou; bidx = p; }  // ascending p: first max
        }
        // best >= 0 always (iou >= 0): float bits order-preserving
        unsigned long long pk =
            ((unsigned long long)__float_as_uint(best) << 32)
            | (unsigned)(0xFFFFFFFFu - (unsigned)bidx);
#pragma unroll
        for (int d = 32; d; d >>= 1) {
            unsigned long long o = __shfl_xor(pk, d);
            if (o > pk) pk = o;
        }
        if (lane == 0) bp_part[(part * B + b) * G + g] = pk;
    }
}

// ---------------------------------------------------------------------------
// Kernel 2 (mega): main streaming + per-batch topk continuation + final.
// Main: per (b,p) inline IoU argmax over G, forced-prior override (8-part
// max combine), box loss, CE loss, mined value; conf staged global->reg
// (static float4 x11) -> LDS. Partials by plain store.
// Continuation (last block of batch b, per-batch PADDED counter): 3-level
// radix select (11+11+10, 2048-bin hist on sconf overlay) -> neg_b[b].
// Final (last of 32 continuations): reduce partials + neg_b -> out.
// ---------------------------------------------------------------------------
__global__ __launch_bounds__(TM) void k_mega(
    const float* __restrict__ loc_data, const float* __restrict__ conf_data,
    const float* __restrict__ priors, const float* __restrict__ gt,
    const int* __restrict__ labels,
    const unsigned long long* __restrict__ bp_part,
    float* __restrict__ mined, float4* __restrict__ partial,
    float* __restrict__ neg_b, int* __restrict__ counters,
    float* __restrict__ out) {
    int b = blockIdx.y;
    int p0 = blockIdx.x * TM;
    int tid = threadIdx.x;
    int p = p0 + tid;
    int lane = tid & 63, wid = tid >> 6;
    __shared__ float sconf[TM * C];        // 21 KB; hist overlay in continuation
    __shared__ int sforce[G];
    __shared__ float4 sg[G];
    __shared__ float sarea[G];
    if (tid < G) {
        unsigned long long mx = 0ull;
#pragma unroll
        for (int q = 0; q < NPART; ++q) {
            unsigned long long v = bp_part[(q * B + b) * G + tid];
            mx = v > mx ? v : mx;
        }
        sforce[tid] = (int)(0xFFFFFFFFu - (unsigned)mx);
        float4 g4 = reinterpret_cast<const float4*>(gt)[b * G + tid];
        sg[tid] = g4;
        sarea[tid] = (g4.z - g4.x) * (g4.w - g4.y);
    }
    int valid = min(TM, P - p0);
    size_t gbase = ((size_t)b * P + p0) * C;
    int tot4 = (valid * C) >> 2;          // exact: 128*41 and 48*41 both %4==0
    const float4* g4p = reinterpret_cast<const float4*>(conf_data + gbase);
    float4* s4 = reinterpret_cast<float4*>(sconf);
    float4 r0, r1, r2, r3, r4, r5, r6, r7, r8, r9, r10;
#define LD(j, rj) { int i = tid + (j) * TM; if (i < tot4) rj = g4p[i]; }
#define ST(j, rj) { int i = tid + (j) * TM; if (i < tot4) s4[i] = rj; }
    LD(0, r0) LD(1, r1) LD(2, r2) LD(3, r3) LD(4, r4) LD(5, r5)
    LD(6, r6) LD(7, r7) LD(8, r8) LD(9, r9) LD(10, r10)
    ST(0, r0) ST(1, r1) ST(2, r2) ST(3, r3) ST(4, r4) ST(5, r5)
    ST(6, r6) ST(7, r7) ST(8, r8) ST(9, r9) ST(10, r10)
#undef LD
#undef ST
    __syncthreads();

    float my_box = 0.0f, my_posc = 0.0f; int my_pos = 0;
    if (p < P) {
        float4 pr = reinterpret_cast<const float4*>(priors)[p];
        float px1 = pr.x - pr.z * 0.5f, py1 = pr.y - pr.w * 0.5f;
        float px2 = pr.x + pr.z * 0.5f, py2 = pr.y + pr.w * 0.5f;
        float parea = (px2 - px1) * (py2 - py1);
        float ov = -1.0f; int bidx = 0;
#pragma unroll
        for (int g = 0; g < G; ++g) {
            float4 gb = sg[g];
            float lx = fmaxf(gb.x, px1), ly = fmaxf(gb.y, py1);
            float rx = fminf(gb.z, px2), ry = fminf(gb.w, py2);
            float w = fmaxf(rx - lx, 0.0f), h = fmaxf(ry - ly, 0.0f);
            float inter = w * h;
            float iou = inter / (sarea[g] + parea - inter);
            if (iou > ov) { ov = iou; bidx = g; }   // strict > keeps FIRST g
        }
        int fidx = -1;
#pragma unroll
        for (int g = 0; g < G; ++g)
            if (p == sforce[g]) fidx = g;             // ascending g: LAST wins
        bool pos = false, neutral = false;
        int gidx = 0, cls = 0;
        float boxl = 0.0f;
        if (fidx >= 0)            { pos = true; gidx = fidx; }
        else if (ov >= POS_TH)    { pos = true; gidx = bidx; }
        else if (ov >= NEG_TH)    { neutral = true; }
        if (pos) {
            cls = labels[b * G + gidx] + 1;
            float4 gb = sg[gidx];
            float mcx = (gb.x + gb.z) * 0.5f, mcy = (gb.y + gb.w) * 0.5f;
            float tx = (mcx - pr.x) / (0.1f * pr.z);
            float ty = (mcy - pr.y) / (0.1f * pr.w);
            float tw = __logf(fmaxf((gb.z - gb.x) / pr.z, 1e-8f)) / 0.2f;
            float th = __logf(fmaxf((gb.w - gb.y) / pr.w, 1e-8f)) / 0.2f;
            float4 ld = reinterpret_cast<const float4*>(loc_data)[b * P + p];
            boxl = sl1(ld.x - tx) + sl1(ld.y - ty) + sl1(ld.z - tw) + sl1(ld.w - th);
        }
        const float* cv = &sconf[tid * C];
        float mx = cv[0];
#pragma unroll
        for (int c = 1; c < C; ++c) mx = fmaxf(mx, cv[c]);
        float se = 0.0f;
#pragma unroll
        for (int c = 0; c < C; ++c) se += __expf(cv[c] - mx);
        float lse = mx + __logf(se);
        float lc = lse - cv[cls];          // >= 0 always (lse >= mx >= picked)
        mined[(size_t)b * P + p] = (pos || neutral) ? 0.0f : lc;
        my_pos = pos ? 1 : 0;
        my_box = boxl;
        my_posc = pos ? lc : 0.0f;
    }

#pragma unroll
    for (int d = 32; d; d >>= 1) {
        my_box  += __shfl_xor(my_box, d);
        my_posc += __shfl_xor(my_posc, d);
        my_pos  += __shfl_xor(my_pos, d);
    }
    __shared__ float rb[2], rc[2]; __shared__ int rp[2];
    if (lane == 0) { rb[wid] = my_box; rc[wid] = my_posc; rp[wid] = my_pos; }
    __syncthreads();

    // ---- election: last block of batch b continues into topk ----
    __shared__ bool amlast;
    if (tid == 0) {
        partial[b * PBM + blockIdx.x] =
            make_float4(rb[0] + rb[1], rc[0] + rc[1], (float)(rp[0] + rp[1]), 0.0f);
        __threadfence();                              // release mined+partial
        int old = atomicAdd(&counters[(1 + b) * CPAD], 1);   // own 128B line
        amlast = (old == PBM - 1);
    }
    __syncthreads();
    if (!amlast) return;
    __threadfence();                                  // acquire others' stores

    // ================= continuation: topk for batch b =================
    const float4* mb4 = reinterpret_cast<const float4*>(mined + (size_t)b * P);
    int cnt = 0;
    for (int i = tid; i < PBM; i += TM) cnt += (int)partial[b * PBM + i].z;
#pragma unroll
    for (int d = 32; d; d >>= 1) cnt += __shfl_xor(cnt, d);
    __shared__ int ired[2];
    if (lane == 0) ired[wid] = cnt;
    __syncthreads();
    int np = ired[0] + ired[1];
    int k = 3 * np; if (k > P - 1) k = P - 1;

    float negval = 0.0f;                  // valid on tid 0
    if (k > 0) {                          // block-uniform
        unsigned* hist = reinterpret_cast<unsigned*>(sconf);   // 2048 bins overlay
        __shared__ unsigned sel[3];       // [0]=prefix, [1]=want, [2]=cnt_gt
        __shared__ unsigned usuf[2];
        if (tid == 0) { sel[0] = 0u; sel[1] = (unsigned)k; sel[2] = 0u; }
        const int shifts[3] = {21, 10, 0};
        const int widths[3] = {11, 11, 10};
#pragma unroll
        for (int level = 0; level < 3; ++level) {
            int shift = shifts[level];
            unsigned bmask = (1u << widths[level]) - 1u;
            for (int i = tid; i < 2048; i += TM) hist[i] = 0u;
            __syncthreads();
            unsigned pref = sel[0];
            unsigned pmask = level ? (0xFFFFFFFFu << (shift + widths[level])) : 0u;
            for (int i = tid; i < P4; i += TM) {
                float4 v4 = mb4[i];
                unsigned v;
                v = __float_as_uint(v4.x); if ((v & pmask) == pref) atomicAdd(&hist[(v >> shift) & bmask], 1u);
                v = __float_as_uint(v4.y); if ((v & pmask) == pref) atomicAdd(&hist[(v >> shift) & bmask], 1u);
                v = __float_as_uint(v4.z); if ((v & pmask) == pref) atomicAdd(&hist[(v >> shift) & bmask], 1u);
                v = __float_as_uint(v4.w); if ((v & pmask) == pref) atomicAdd(&hist[(v >> shift) & bmask], 1u);
            }
            __syncthreads();
            // selection: thread owns bins [16*tid, 16*tid+16)
            unsigned tsum = 0;
#pragma unroll
            for (int j = 0; j < 16; ++j) tsum += hist[16 * tid + j];
            unsigned x = tsum;
#pragma unroll
            for (int d = 1; d < 64; d <<= 1) {
                unsigned t = __shfl_down(x, d);
                if (lane + d < 64) x += t;
            }
            if (lane == 0) usuf[wid] = x;             // per-wave total
            __syncthreads();
            unsigned S_own = x + ((wid == 0) ? usuf[1] : 0u);  // suffix incl own
            unsigned want = sel[1];
            __syncthreads();                          // all read want before writes
            unsigned cur = S_own - tsum;              // S(16t+16)
#pragma unroll
            for (int j = 15; j >= 0; --j) {
                unsigned h = hist[16 * tid + j];
                unsigned nxt = cur + h;
                if (cur < want && want <= nxt) {      // unique crossing bin
                    sel[0] = pref | (((unsigned)(16 * tid + j) & bmask) << shift);
                    sel[1] = want - cur;
                    sel[2] += cur;
                }
                cur = nxt;
            }
            __syncthreads();
        }
        unsigned vk = sel[0];
        unsigned cnt_gt = sel[2];
        float vkf = __uint_as_float(vk);
        float ssum = 0.0f;
        for (int i = tid; i < P4; i += TM) {
            float4 v4 = mb4[i];
            if (__float_as_uint(v4.x) > vk) ssum += v4.x;
            if (__float_as_uint(v4.y) > vk) ssum += v4.y;
            if (__float_as_uint(v4.z) > vk) ssum += v4.z;
            if (__float_as_uint(v4.w) > vk) ssum += v4.w;
        }
#pragma unroll
        for (int d = 32; d; d >>= 1) ssum += __shfl_xor(ssum, d);
        __shared__ float fs[2];
        if (lane == 0) fs[wid] = ssum;
        __syncthreads();
        if (tid == 0)
            negval = fs[0] + fs[1] + (float)(k - (int)cnt_gt) * vkf;
    }

    // ---- publish neg_b, last continuation finalizes ----
    __shared__ bool amfinal;
    if (tid == 0) {
        neg_b[b] = negval;
        __threadfence();
        int old = atomicAdd(&counters[0], 1);         // 32 adds total: cheap
        amfinal = (old == B - 1);
    }
    __syncthreads();
    if (!amfinal) return;
    __threadfence();

    float sbx = 0.0f, sc = 0.0f, sp2 = 0.0f, sn = 0.0f;
    for (int i = tid; i < B * PBM; i += TM) {
        float4 v = partial[i];
        sbx += v.x; sc += v.y; sp2 += v.z;
    }
    if (tid < B) sn = neg_b[tid];
#pragma unroll
    for (int d = 32; d; d >>= 1) {
        sbx += __shfl_xor(sbx, d);
        sc  += __shfl_xor(sc, d);
        sp2 += __shfl_xor(sp2, d);
        sn  += __shfl_xor(sn, d);
    }
    __shared__ float fr[2][4];
    if (lane == 0) { fr[wid][0] = sbx; fr[wid][1] = sc; fr[wid][2] = sp2; fr[wid][3] = sn; }
    __syncthreads();
    if (tid == 0) {
        float tb = fr[0][0] + fr[1][0], tc = fr[0][1] + fr[1][1];
        float tp = fr[0][2] + fr[1][2], tn = fr[0][3] + fr[1][3];
        float npos = fmaxf(tp, 1.0f);
        out[0] = tb / npos * 1.5f + (tc + tn) / npos * 6.5f;
    }
}

extern "C" void kernel_launch(void* const* d_in, const int* in_sizes, int n_in,
                              void* d_out, int out_size, void* d_ws, size_t ws_size,
                              hipStream_t stream) {
    const float* loc    = (const float*)d_in[0];
    const float* conf   = (const float*)d_in[1];
    const float* priors = (const float*)d_in[2];
    const float* gt     = (const float*)d_in[3];
    const int*   labels = (const int*)d_in[4];
    float* out = (float*)d_out;

    char* w = (char*)d_ws;
    float4* partial = (float4*)w;                      w += sizeof(float4) * B * PBM;
    float* mined  = (float*)w;                         w += sizeof(float) * B * P;
    unsigned long long* bp_part = (unsigned long long*)w;
    w += sizeof(unsigned long long) * NPART * B * G;
    float* negb   = (float*)w;                         w += sizeof(float) * B;
    int*   counters = (int*)w;                         w += sizeof(int) * (B + 1) * CPAD;

    // 2 graph nodes. bp_part/partial/mined/negb fully overwritten each call;
    // padded counters zeroed inside k_match (node 1) before k_mega (node 2).
    k_match<<<dim3(NPART, B), 1024, 0, stream>>>(priors, gt, bp_part, counters);
    k_mega<<<dim3(PBM, B), TM, 0, stream>>>(loc, conf, priors, gt, labels,
                                            bp_part, mined, partial,
                                            negb, counters, out);
}

// Round 8
// 81.210 us; speedup vs baseline: 15.3467x; 3.1694x over previous
//
#include <hip/hip_runtime.h>

// Problem constants (from reference setup_inputs)
static constexpr int B = 32;
static constexpr int P = 19248;
static constexpr int G = 32;
static constexpr int C = 41;          // num classes
static constexpr float POS_TH = 0.5f;
static constexpr float NEG_TH = 0.4f;

static constexpr int TM = 128;                   // k_main block size
static constexpr int PBM = (P + TM - 1) / TM;    // 151 tiles per batch
static constexpr int NPART = 8;                  // k_match prior partitions
static constexpr int PPART = P / NPART;          // 2406 (exact)
static constexpr int P4 = P / 4;                 // 4812 float4 per batch

__device__ __forceinline__ float sl1(float d) {
    d = fabsf(d);
    return d < 1.0f ? 0.5f * d * d : d - 0.5f;
}

// ---------------------------------------------------------------------------
// Kernel 1: per (b,g) best prior (R5-proven wave-per-g form). Grid (NPART,B)
// x 1024. Wave w handles g = w, w+16 over its prior part: per-lane running
// best (ascending p + strict > = first-max), packed-u64 wave reduce
// ((iou_bits<<32)|~p -> higher IoU, then smaller p). Plain stores, no
// atomics. Block (0,0) zeroes the topk done-counter.
// ---------------------------------------------------------------------------
__global__ __launch_bounds__(1024) void k_match(
    const float* __restrict__ priors, const float* __restrict__ gt,
    unsigned long long* __restrict__ bp_part, int* __restrict__ done) {
    int part = blockIdx.x, b = blockIdx.y;
    if (part == 0 && b == 0 && threadIdx.x == 0) *done = 0;
    int lane = threadIdx.x & 63, wid = threadIdx.x >> 6;
    int pbase = part * PPART;
#pragma unroll
    for (int gsub = 0; gsub < 2; ++gsub) {
        int g = wid + gsub * 16;
        float4 gb = reinterpret_cast<const float4*>(gt)[b * G + g]; // broadcast
        float ga = (gb.z - gb.x) * (gb.w - gb.y);
        float best = -1.0f; int bidx = 0;
        for (int i = lane; i < PPART; i += 64) {
            int p = pbase + i;
            float4 pr = reinterpret_cast<const float4*>(priors)[p];
            float px1 = pr.x - pr.z * 0.5f, py1 = pr.y - pr.w * 0.5f;
            float px2 = pr.x + pr.z * 0.5f, py2 = pr.y + pr.w * 0.5f;
            float parea = (px2 - px1) * (py2 - py1);
            float lx = fmaxf(gb.x, px1), ly = fmaxf(gb.y, py1);
            float rx = fminf(gb.z, px2), ry = fminf(gb.w, py2);
            float w = fmaxf(rx - lx, 0.0f), h = fmaxf(ry - ly, 0.0f);
            float inter = w * h;
            float iou = inter / (ga + parea - inter);
            if (iou > best) { best = iou; bidx = p; }  // ascending p: first max
        }
        // best >= 0 always (iou >= 0): float bits order-preserving
        unsigned long long pk =
            ((unsigned long long)__float_as_uint(best) << 32)
            | (unsigned)(0xFFFFFFFFu - (unsigned)bidx);
#pragma unroll
        for (int d = 32; d; d >>= 1) {
            unsigned long long o = __shfl_xor(pk, d);
            if (o > pk) pk = o;
        }
        if (lane == 0) bp_part[(part * B + b) * G + g] = pk;
    }
}

// ---------------------------------------------------------------------------
// Kernel 2: main streaming kernel (R5-proven: no fences, no atomics, plain
// partial stores). 128 threads, 21 KB LDS -> 7 blocks/CU. Per (b,p): inline
// IoU argmax over G, forced-prior override (8-part max combine), box loss,
// CE loss, mined value. conf staged global->reg (static float4 x11) -> LDS.
// ---------------------------------------------------------------------------
__global__ __launch_bounds__(TM) void k_main(
    const float* __restrict__ loc_data, const float* __restrict__ conf_data,
    const float* __restrict__ priors, const float* __restrict__ gt,
    const int* __restrict__ labels,
    const unsigned long long* __restrict__ bp_part,
    float* __restrict__ mined, float4* __restrict__ partial) {
    int b = blockIdx.y;
    int p0 = blockIdx.x * TM;
    int tid = threadIdx.x;
    int p = p0 + tid;
    int lane = tid & 63, wid = tid >> 6;
    __shared__ float sconf[TM * C];
    __shared__ int sforce[G];
    __shared__ float4 sg[G];
    __shared__ float sarea[G];
    if (tid < G) {
        unsigned long long mx = 0ull;
#pragma unroll
        for (int q = 0; q < NPART; ++q) {
            unsigned long long v = bp_part[(q * B + b) * G + tid];
            mx = v > mx ? v : mx;
        }
        sforce[tid] = (int)(0xFFFFFFFFu - (unsigned)mx);
        float4 g4 = reinterpret_cast<const float4*>(gt)[b * G + tid];
        sg[tid] = g4;
        sarea[tid] = (g4.z - g4.x) * (g4.w - g4.y);
    }
    int valid = min(TM, P - p0);
    size_t gbase = ((size_t)b * P + p0) * C;
    int tot4 = (valid * C) >> 2;          // exact: 128*41 and 48*41 both %4==0
    const float4* g4p = reinterpret_cast<const float4*>(conf_data + gbase);
    float4* s4 = reinterpret_cast<float4*>(sconf);
    float4 r0, r1, r2, r3, r4, r5, r6, r7, r8, r9, r10;
#define LD(j, rj) { int i = tid + (j) * TM; if (i < tot4) rj = g4p[i]; }
#define ST(j, rj) { int i = tid + (j) * TM; if (i < tot4) s4[i] = rj; }
    LD(0, r0) LD(1, r1) LD(2, r2) LD(3, r3) LD(4, r4) LD(5, r5)
    LD(6, r6) LD(7, r7) LD(8, r8) LD(9, r9) LD(10, r10)
    ST(0, r0) ST(1, r1) ST(2, r2) ST(3, r3) ST(4, r4) ST(5, r5)
    ST(6, r6) ST(7, r7) ST(8, r8) ST(9, r9) ST(10, r10)
#undef LD
#undef ST
    __syncthreads();

    float my_box = 0.0f, my_posc = 0.0f; int my_pos = 0;
    if (p < P) {
        float4 pr = reinterpret_cast<const float4*>(priors)[p];
        float px1 = pr.x - pr.z * 0.5f, py1 = pr.y - pr.w * 0.5f;
        float px2 = pr.x + pr.z * 0.5f, py2 = pr.y + pr.w * 0.5f;
        float parea = (px2 - px1) * (py2 - py1);
        float ov = -1.0f; int bidx = 0;
#pragma unroll
        for (int g = 0; g < G; ++g) {
            float4 gb = sg[g];
            float lx = fmaxf(gb.x, px1), ly = fmaxf(gb.y, py1);
            float rx = fminf(gb.z, px2), ry = fminf(gb.w, py2);
            float w = fmaxf(rx - lx, 0.0f), h = fmaxf(ry - ly, 0.0f);
            float inter = w * h;
            float iou = inter / (sarea[g] + parea - inter);
            if (iou > ov) { ov = iou; bidx = g; }   // strict > keeps FIRST g
        }
        int fidx = -1;
#pragma unroll
        for (int g = 0; g < G; ++g)
            if (p == sforce[g]) fidx = g;             // ascending g: LAST wins
        bool pos = false, neutral = false;
        int gidx = 0, cls = 0;
        float boxl = 0.0f;
        if (fidx >= 0)            { pos = true; gidx = fidx; }
        else if (ov >= POS_TH)    { pos = true; gidx = bidx; }
        else if (ov >= NEG_TH)    { neutral = true; }
        if (pos) {
            cls = labels[b * G + gidx] + 1;
            float4 gb = sg[gidx];
            float mcx = (gb.x + gb.z) * 0.5f, mcy = (gb.y + gb.w) * 0.5f;
            float tx = (mcx - pr.x) / (0.1f * pr.z);
            float ty = (mcy - pr.y) / (0.1f * pr.w);
            float tw = __logf(fmaxf((gb.z - gb.x) / pr.z, 1e-8f)) / 0.2f;
            float th = __logf(fmaxf((gb.w - gb.y) / pr.w, 1e-8f)) / 0.2f;
            float4 ld = reinterpret_cast<const float4*>(loc_data)[b * P + p];
            boxl = sl1(ld.x - tx) + sl1(ld.y - ty) + sl1(ld.z - tw) + sl1(ld.w - th);
        }
        const float* cv = &sconf[tid * C];
        float mx = cv[0];
#pragma unroll
        for (int c = 1; c < C; ++c) mx = fmaxf(mx, cv[c]);
        float se = 0.0f;
#pragma unroll
        for (int c = 0; c < C; ++c) se += __expf(cv[c] - mx);
        float lse = mx + __logf(se);
        float lc = lse - cv[cls];          // >= 0 always (lse >= mx >= picked)
        mined[(size_t)b * P + p] = (pos || neutral) ? 0.0f : lc;
        my_pos = pos ? 1 : 0;
        my_box = boxl;
        my_posc = pos ? lc : 0.0f;
    }

#pragma unroll
    for (int d = 32; d; d >>= 1) {
        my_box  += __shfl_xor(my_box, d);
        my_posc += __shfl_xor(my_posc, d);
        my_pos  += __shfl_xor(my_pos, d);
    }
    __shared__ float rb[2], rc[2]; __shared__ int rp[2];
    if (lane == 0) { rb[wid] = my_box; rc[wid] = my_posc; rp[wid] = my_pos; }
    __syncthreads();
    if (tid == 0) {
        partial[b * PBM + blockIdx.x] =
            make_float4(rb[0] + rb[1], rc[0] + rc[1], (float)(rp[0] + rp[1]), 0.0f);
    }
}

// ---------------------------------------------------------------------------
// Kernel 3: per batch, sum of top-k of mined (k = min(3*npos_b, P-1)) via
// 3-level radix select (11+11+10 bits, 2048-bin hist), float4 passes,
// parallel suffix-scan selection (2 bins/thread). LAST block (done counter,
// O(32) fences only — proven cheap in R5) reduces partials + neg_b -> out.
// ---------------------------------------------------------------------------
__global__ __launch_bounds__(1024) void k_topk(
    const float* __restrict__ mined, const float4* __restrict__ partial,
    float* __restrict__ neg_b, int* __restrict__ done,
    float* __restrict__ out) {
    int b = blockIdx.x;
    const float4* mb4 = reinterpret_cast<const float4*>(mined + (size_t)b * P);
    int tid = threadIdx.x;
    int lane = tid & 63, wid = tid >> 6;

    // npos for this batch from partials
    int cnt = 0;
    if (tid < PBM) cnt = (int)partial[b * PBM + tid].z;
#pragma unroll
    for (int d = 32; d; d >>= 1) cnt += __shfl_xor(cnt, d);
    __shared__ int ired[16];
    if (lane == 0) ired[wid] = cnt;
    __syncthreads();
    int np = 0;
#pragma unroll
    for (int w2 = 0; w2 < 16; ++w2) np += ired[w2];
    int k = 3 * np; if (k > P - 1) k = P - 1;

    float negval = 0.0f;                  // valid on tid 0
    if (k > 0) {                          // block-uniform
        __shared__ unsigned hist[2048];
        __shared__ unsigned sel[3];       // [0]=prefix, [1]=want, [2]=cnt_gt
        __shared__ unsigned wtot[16];
        if (tid == 0) { sel[0] = 0u; sel[1] = (unsigned)k; sel[2] = 0u; }
        const int shifts[3] = {21, 10, 0};
        const int widths[3] = {11, 11, 10};
#pragma unroll
        for (int level = 0; level < 3; ++level) {
            int shift = shifts[level];
            unsigned bmask = (1u << widths[level]) - 1u;
            hist[tid] = 0u; hist[tid + 1024] = 0u;
            __syncthreads();
            unsigned pref = sel[0];
            unsigned pmask = level ? (0xFFFFFFFFu << (shift + widths[level])) : 0u;
            for (int i = tid; i < P4; i += 1024) {
                float4 v4 = mb4[i];
                unsigned v;
                v = __float_as_uint(v4.x); if ((v & pmask) == pref) atomicAdd(&hist[(v >> shift) & bmask], 1u);
                v = __float_as_uint(v4.y); if ((v & pmask) == pref) atomicAdd(&hist[(v >> shift) & bmask], 1u);
                v = __float_as_uint(v4.z); if ((v & pmask) == pref) atomicAdd(&hist[(v >> shift) & bmask], 1u);
                v = __float_as_uint(v4.w); if ((v & pmask) == pref) atomicAdd(&hist[(v >> shift) & bmask], 1u);
            }
            __syncthreads();
            // parallel suffix-scan selection: thread owns bins 2t, 2t+1
            unsigned h0 = hist[2 * tid], h1 = hist[2 * tid + 1];
            unsigned x = h0 + h1;
#pragma unroll
            for (int d = 1; d < 64; d <<= 1) {
                unsigned t = __shfl_down(x, d);
                if (lane + d < 64) x += t;
            }
            if (lane == 0) wtot[wid] = x;
            __syncthreads();
            unsigned above = 0;
            for (int w2 = wid + 1; w2 < 16; ++w2) above += wtot[w2];
            unsigned sp = x + above;             // S(2t): suffix from bin 2t
            unsigned s2 = sp - h0 - h1;          // S(2t+2)
            unsigned s1 = s2 + h1;               // S(2t+1)
            unsigned want = sel[1];
            __syncthreads();                     // all read want before writes
            if (s1 >= want && s2 < want) {       // bin 2t+1 crosses
                sel[0] = pref | (((2u * (unsigned)tid + 1u) & bmask) << shift);
                sel[1] = want - s2;
                sel[2] += s2;
            } else if (sp >= want && s1 < want) {// bin 2t crosses
                sel[0] = pref | (((2u * (unsigned)tid) & bmask) << shift);
                sel[1] = want - s1;
                sel[2] += s1;
            }
            __syncthreads();
        }
        unsigned vk = sel[0];
        unsigned cnt_gt = sel[2];
        float vkf = __uint_as_float(vk);
        float ssum = 0.0f;
        for (int i = tid; i < P4; i += 1024) {
            float4 v4 = mb4[i];
            if (__float_as_uint(v4.x) > vk) ssum += v4.x;
            if (__float_as_uint(v4.y) > vk) ssum += v4.y;
            if (__float_as_uint(v4.z) > vk) ssum += v4.z;
            if (__float_as_uint(v4.w) > vk) ssum += v4.w;
        }
#pragma unroll
        for (int d = 32; d; d >>= 1) ssum += __shfl_xor(ssum, d);
        __shared__ float rs[16];
        if (lane == 0) rs[wid] = ssum;
        __syncthreads();
        if (tid == 0) {
            float tot = 0.0f;
#pragma unroll
            for (int w2 = 0; w2 < 16; ++w2) tot += rs[w2];
            negval = tot + (float)(k - (int)cnt_gt) * vkf;
        }
    }

    // completion protocol (O(32) device-scope fences total — proven cheap)
    __shared__ bool islast;
    if (tid == 0) {
        neg_b[b] = negval;
        __threadfence();                       // release neg_b
        int old = atomicAdd(done, 1);
        islast = (old == B - 1);
    }
    __syncthreads();
    if (!islast) return;
    __threadfence();                           // acquire other blocks' neg_b

    float sbx = 0.0f, sc = 0.0f, sp2 = 0.0f, sn = 0.0f;
    for (int i = tid; i < B * PBM; i += 1024) {
        float4 v = partial[i];
        sbx += v.x; sc += v.y; sp2 += v.z;
    }
    if (tid < B) sn = neg_b[tid];
#pragma unroll
    for (int d = 32; d; d >>= 1) {
        sbx += __shfl_xor(sbx, d);
        sc  += __shfl_xor(sc, d);
        sp2 += __shfl_xor(sp2, d);
        sn  += __shfl_xor(sn, d);
    }
    __shared__ float fr[16][4];
    if (lane == 0) { fr[wid][0] = sbx; fr[wid][1] = sc; fr[wid][2] = sp2; fr[wid][3] = sn; }
    __syncthreads();
    if (tid == 0) {
        float tb = 0, tc = 0, tp = 0, tn = 0;
#pragma unroll
        for (int w2 = 0; w2 < 16; ++w2) {
            tb += fr[w2][0]; tc += fr[w2][1]; tp += fr[w2][2]; tn += fr[w2][3];
        }
        float npos = fmaxf(tp, 1.0f);
        out[0] = tb / npos * 1.5f + (tc + tn) / npos * 6.5f;
    }
}

extern "C" void kernel_launch(void* const* d_in, const int* in_sizes, int n_in,
                              void* d_out, int out_size, void* d_ws, size_t ws_size,
                              hipStream_t stream) {
    const float* loc    = (const float*)d_in[0];
    const float* conf   = (const float*)d_in[1];
    const float* priors = (const float*)d_in[2];
    const float* gt     = (const float*)d_in[3];
    const int*   labels = (const int*)d_in[4];
    float* out = (float*)d_out;

    char* w = (char*)d_ws;
    float4* partial = (float4*)w;                      w += sizeof(float4) * B * PBM;
    float* mined  = (float*)w;                         w += sizeof(float) * B * P;
    unsigned long long* bp_part = (unsigned long long*)w;
    w += sizeof(unsigned long long) * NPART * B * G;
    float* negb   = (float*)w;                         w += sizeof(float) * B;
    int*   done   = (int*)w;                           w += sizeof(int);

    // 3 graph nodes. bp_part/partial/mined/negb fully overwritten each call;
    // done zeroed inside k_match (node 1).
    k_match<<<dim3(NPART, B), 1024, 0, stream>>>(priors, gt, bp_part, done);
    k_main<<<dim3(PBM, B), TM, 0, stream>>>(loc, conf, priors, gt, labels,
                                            bp_part, mined, partial);
    k_topk<<<B, 1024, 0, stream>>>(mined, partial, negb, done, out);
}